// Round 1
// baseline (139.229 us; speedup 1.0000x reference)
//
#include <hip/hip_runtime.h>
#include <hip/hip_bf16.h>

#define NB 8
#define NN 256
#define DIMV 256
#define DI 64
#define NEGMAX 3.402823466e+38f

typedef unsigned short u16;
typedef __attribute__((ext_vector_type(8))) short bf16x8;
typedef __attribute__((ext_vector_type(4))) float f32x4;

__device__ __forceinline__ float bf2f(u16 u) {
    union { unsigned int ui; float f; } x; x.ui = ((unsigned int)u) << 16; return x.f;
}
__device__ __forceinline__ u16 f2bf(float f) {
    union { float f; unsigned int u; } x; x.f = f;
    unsigned int r = x.u + 0x7FFFu + ((x.u >> 16) & 1u);
    return (u16)(r >> 16);
}

// ---------------------------------------------------------------------------
// prep 1: transpose + bf16-convert the three GEMM B-operand weights
//   w1t[o][k]  = attn_w1[k][o]   (256 x 64)
//   w2t[d][h]  = attn_w2[h][d]   (64 x 256)
//   pw2t[d][h] = pos_w2[h][d]    (64 x 64)
// ---------------------------------------------------------------------------
__global__ void prep_w(const float* __restrict__ w1, const float* __restrict__ w2,
                       const float* __restrict__ pw2,
                       u16* __restrict__ w1t, u16* __restrict__ w2t, u16* __restrict__ pw2t)
{
    int idx = blockIdx.x * 256 + threadIdx.x;   // 64 blocks -> 16384 threads
    if (idx < 16384) {
        { int o = idx >> 6, kk = idx & 63;  w1t[idx] = f2bf(w1[kk * 256 + o]); }
        { int d = idx >> 8, h  = idx & 255; w2t[idx] = f2bf(w2[h * 64 + d]); }
    }
    if (idx < 4096) { int d = idx >> 6, h = idx & 63; pw2t[idx] = f2bf(pw2[h * 64 + d]); }
}

// ---------------------------------------------------------------------------
// prep 2: q = x@theta_w, k = y@phi_w, v = y@g_w   (all (B,N,64) f32 into ws)
// block = (b, 4 rows of n), 256 threads: thread (nl = t>>6, d = t&63)
// ---------------------------------------------------------------------------
__global__ void prep_qkv(const float* __restrict__ x, const float* __restrict__ y,
                         const float* __restrict__ tw, const float* __restrict__ pw,
                         const float* __restrict__ gw,
                         float* __restrict__ q, float* __restrict__ k, float* __restrict__ v)
{
    __shared__ float xs[4][256];
    __shared__ float ys[4][256];
    const int blk = blockIdx.x;              // 512 = 8 b * 64 groups
    const int b = blk >> 6;
    const int n0 = (blk & 63) * 4;
    const int tid = threadIdx.x;
    {
        int r = tid >> 6, e = tid & 63;
        ((float4*)xs[r])[e] = ((const float4*)(x + (size_t)(b * NN + n0 + r) * DIMV))[e];
        ((float4*)ys[r])[e] = ((const float4*)(y + (size_t)(b * NN + n0 + r) * DIMV))[e];
    }
    __syncthreads();
    const int nl = tid >> 6, d = tid & 63;
    float aq = 0.f, ak = 0.f, av = 0.f;
    #pragma unroll 4
    for (int c = 0; c < 256; ++c) {
        float wq = tw[c * 64 + d], wk = pw[c * 64 + d], wv = gw[c * 64 + d];
        float xv = xs[nl][c], yv = ys[nl][c];
        aq += xv * wq; ak += yv * wk; av += yv * wv;
    }
    const int n = n0 + nl;
    q[(b * NN + n) * DI + d] = aq;
    k[(b * NN + n) * DI + d] = ak;
    v[(b * NN + n) * DI + d] = av;
}

// ---------------------------------------------------------------------------
// main fused kernel: one block per (b, i); 256 threads = 4 waves.
// wave w privately owns j-rows [w*64, w*64+64).
// ---------------------------------------------------------------------------
__global__ __launch_bounds__(256, 2)
void fused_attn(const float* __restrict__ x, const float* __restrict__ x_pos,
                const float* __restrict__ y_pos, const int* __restrict__ mask,
                const float* __restrict__ pw1, const float* __restrict__ pb1,
                const float* __restrict__ pb2,
                const float* __restrict__ ab1, const float* __restrict__ ab2,
                const float* __restrict__ out_w,
                const float* __restrict__ qg, const float* __restrict__ kg,
                const float* __restrict__ vg,
                const u16* __restrict__ w1t, const u16* __restrict__ w2t,
                const u16* __restrict__ pw2t,
                float* __restrict__ out)
{
    __shared__ u16 sA[NN * DI];   // 32 KB: hidden -> T (swizzled) -> SIM (plain)
    __shared__ u16 sB[NN * 32];   // 16 KB: H-chunk (swizzled); overlays: q, reductions
    __shared__ u16 sV[NN * DI];   // 32 KB: v_full bf16 (plain)
    float* sBf = (float*)sB;

    const int blk = blockIdx.x;
    const int b = blk >> 8;
    const int i = blk & 255;
    const int tid = threadIdx.x;
    const int l   = tid & 63;
    const int w   = tid >> 6;
    const int j0  = w * 64;
    const int l15 = l & 15;
    const int lh  = l >> 4;

    char* sAB = (char*)sA;
    char* sBB = (char*)sB;

    // ---- phase 0: pos-MLP layer 1 (per-thread row j = tid), q row to LDS ----
    {
        const int j = tid;
        const float xp0 = x_pos[(b * NN + i) * 3 + 0];
        const float xp1 = x_pos[(b * NN + i) * 3 + 1];
        const float xp2 = x_pos[(b * NN + i) * 3 + 2];
        const float r0 = xp0 - y_pos[(b * NN + j) * 3 + 0];
        const float r1 = xp1 - y_pos[(b * NN + j) * 3 + 1];
        const float r2 = xp2 - y_pos[(b * NN + j) * 3 + 2];
        const int sw = (j & 7) << 4;
        #pragma unroll
        for (int h2 = 0; h2 < 32; ++h2) {
            float h0 = pb1[2*h2+0] + r0 * pw1[0*64 + 2*h2+0] + r1 * pw1[1*64 + 2*h2+0] + r2 * pw1[2*64 + 2*h2+0];
            float h1 = pb1[2*h2+1] + r0 * pw1[0*64 + 2*h2+1] + r1 * pw1[1*64 + 2*h2+1] + r2 * pw1[2*64 + 2*h2+1];
            h0 = fmaxf(h0, 0.f); h1 = fmaxf(h1, 0.f);
            unsigned int pk = (unsigned int)f2bf(h0) | ((unsigned int)f2bf(h1) << 16);
            *(unsigned int*)(sAB + ((j * 128 + h2 * 4) ^ sw)) = pk;
        }
    }
    if (tid < 64) sBf[tid] = qg[(b * NN + i) * DI + tid];
    __syncthreads();

    // ---- phase 0b: GEMM0  RPE(256x64) = hidden @ pos_w2 ----
    f32x4 accR[4][4];
    {
        bf16x8 af[4][2], bf[4][2];
        #pragma unroll
        for (int rt = 0; rt < 4; ++rt)
            #pragma unroll
            for (int ks = 0; ks < 2; ++ks) {
                int row = j0 + rt * 16 + l15;
                af[rt][ks] = *(const bf16x8*)(sAB + ((row * 128 + ks * 64 + lh * 16) ^ ((row & 7) << 4)));
            }
        #pragma unroll
        for (int ct = 0; ct < 4; ++ct)
            #pragma unroll
            for (int ks = 0; ks < 2; ++ks) {
                int d = ct * 16 + l15;
                bf[ct][ks] = *(const bf16x8*)((const char*)pw2t + d * 128 + ks * 64 + lh * 16);
            }
        #pragma unroll
        for (int rt = 0; rt < 4; ++rt)
            #pragma unroll
            for (int ct = 0; ct < 4; ++ct) {
                f32x4 a = {0.f, 0.f, 0.f, 0.f};
                a = __builtin_amdgcn_mfma_f32_16x16x32_bf16(af[rt][0], bf[ct][0], a, 0, 0, 0);
                a = __builtin_amdgcn_mfma_f32_16x16x32_bf16(af[rt][1], bf[ct][1], a, 0, 0, 0);
                accR[rt][ct] = a;
            }
    }
    // epilogue: T = q - k + rpe -> sA (swizzled);  v_full = v + rpe -> sV (plain)
    #pragma unroll
    for (int ct = 0; ct < 4; ++ct) {
        const int d = ct * 16 + l15;
        const float pb2v = pb2[d];
        const float qv = sBf[d];
        #pragma unroll
        for (int rt = 0; rt < 4; ++rt)
            #pragma unroll
            for (int r = 0; r < 4; ++r) {
                const int row = j0 + rt * 16 + lh * 4 + r;
                const float rpe = accR[rt][ct][r] + pb2v;
                const float kv = kg[(b * NN + row) * DI + d];
                const float vv = vg[(b * NN + row) * DI + d];
                *(u16*)(sAB + ((row * 128 + d * 2) ^ ((row & 7) << 4))) = f2bf(qv - kv + rpe);
                sV[row * DI + d] = f2bf(vv + rpe);
            }
    }

    // ---- hoist GEMM1 A-fragments (T is loop-invariant) ----
    bf16x8 aT[4][2];
    #pragma unroll
    for (int rt = 0; rt < 4; ++rt)
        #pragma unroll
        for (int ks = 0; ks < 2; ++ks) {
            int row = j0 + rt * 16 + l15;
            aT[rt][ks] = *(const bf16x8*)(sAB + ((row * 128 + ks * 64 + lh * 16) ^ ((row & 7) << 4)));
        }

    // ---- chunk loop: 8 chunks of 32 hidden units; SIM accumulates ----
    f32x4 accS[4][4];
    #pragma unroll
    for (int rt = 0; rt < 4; ++rt)
        #pragma unroll
        for (int ct = 0; ct < 4; ++ct) accS[rt][ct] = (f32x4){0.f, 0.f, 0.f, 0.f};

    for (int hc = 0; hc < 8; ++hc) {
        // GEMM1: Hc(64rows x 32hid) = T @ W1[:, chunk]
        bf16x8 b1f[2][2];
        #pragma unroll
        for (int c2 = 0; c2 < 2; ++c2)
            #pragma unroll
            for (int ks = 0; ks < 2; ++ks) {
                int hid = hc * 32 + c2 * 16 + l15;
                b1f[c2][ks] = *(const bf16x8*)((const char*)w1t + hid * 128 + ks * 64 + lh * 16);
            }
        f32x4 accH[4][2];
        #pragma unroll
        for (int rt = 0; rt < 4; ++rt)
            #pragma unroll
            for (int c2 = 0; c2 < 2; ++c2) {
                f32x4 a = {0.f, 0.f, 0.f, 0.f};
                a = __builtin_amdgcn_mfma_f32_16x16x32_bf16(aT[rt][0], b1f[c2][0], a, 0, 0, 0);
                a = __builtin_amdgcn_mfma_f32_16x16x32_bf16(aT[rt][1], b1f[c2][1], a, 0, 0, 0);
                accH[rt][c2] = a;
            }
        // bias + relu + bf16 -> sHc (sB, swizzled [256][32])
        const float ab1v0 = ab1[hc * 32 + l15];
        const float ab1v1 = ab1[hc * 32 + 16 + l15];
        #pragma unroll
        for (int rt = 0; rt < 4; ++rt)
            #pragma unroll
            for (int r = 0; r < 4; ++r) {
                const int row = j0 + rt * 16 + lh * 4 + r;
                const int sw = (row & 7) << 4;
                *(u16*)(sBB + ((row * 64 + l15 * 2) ^ sw))        = f2bf(fmaxf(accH[rt][0][r] + ab1v0, 0.f));
                *(u16*)(sBB + ((row * 64 + (16 + l15) * 2) ^ sw)) = f2bf(fmaxf(accH[rt][1][r] + ab1v1, 0.f));
            }
        // GEMM2: SIM += Hc @ W2[chunk, :]
        bf16x8 a2[4], b2f[4];
        #pragma unroll
        for (int rt = 0; rt < 4; ++rt) {
            int row = j0 + rt * 16 + l15;
            a2[rt] = *(const bf16x8*)(sBB + ((row * 64 + lh * 16) ^ ((row & 7) << 4)));
        }
        #pragma unroll
        for (int ct = 0; ct < 4; ++ct) {
            int d = ct * 16 + l15;
            b2f[ct] = *(const bf16x8*)((const char*)w2t + d * 512 + hc * 64 + lh * 16);
        }
        #pragma unroll
        for (int rt = 0; rt < 4; ++rt)
            #pragma unroll
            for (int ct = 0; ct < 4; ++ct)
                accS[rt][ct] = __builtin_amdgcn_mfma_f32_16x16x32_bf16(a2[rt], b2f[ct], accS[rt][ct], 0, 0, 0);
    }

    // ---- phase 2: SIM + attn_b2 -> sA plain [256][64] bf16 (own rows only) ----
    #pragma unroll
    for (int ct = 0; ct < 4; ++ct) {
        const int d = ct * 16 + l15;
        const float ab2v = ab2[d];
        #pragma unroll
        for (int rt = 0; rt < 4; ++rt)
            #pragma unroll
            for (int r = 0; r < 4; ++r) {
                const int row = j0 + rt * 16 + lh * 4 + r;
                sA[row * DI + d] = f2bf(accS[rt][ct][r] + ab2v);
            }
    }

    // ---- phase 3: masked softmax over j (cross-wave) + aggregate ----
    __syncthreads();   // all waves done with sB-as-Hc before reduction overlay
    const int mi  = mask[b * NN + i];
    const int mjl = mask[b * NN + j0 + l];
    float m = -NEGMAX;
    for (int r = 0; r < 64; ++r) {
        int mj = __shfl(mjl, r);
        float sv = bf2f(sA[(j0 + r) * DI + l]);
        sv = (mi && mj) ? sv : -NEGMAX;
        m = fmaxf(m, sv);
    }
    float* redm = sBf;         // [4][64]
    float* reds = sBf + 256;
    float* reda = sBf + 512;
    float* sAgg = sBf + 768;
    redm[w * 64 + l] = m;
    __syncthreads();
    const float m4 = fmaxf(fmaxf(redm[l], redm[64 + l]), fmaxf(redm[128 + l], redm[192 + l]));
    float ssum = 0.f, sagg = 0.f;
    for (int r = 0; r < 64; ++r) {
        int mj = __shfl(mjl, r);
        float sv = bf2f(sA[(j0 + r) * DI + l]);
        sv = (mi && mj) ? sv : -NEGMAX;
        float e = __expf(sv - m4);
        ssum += e;
        sagg += e * bf2f(sV[(j0 + r) * DI + l]);
    }
    reds[w * 64 + l] = ssum;
    reda[w * 64 + l] = sagg;
    __syncthreads();
    if (w == 0) {
        float den = reds[l] + reds[64 + l] + reds[128 + l] + reds[192 + l];
        float ag  = reda[l] + reda[64 + l] + reda[128 + l] + reda[192 + l];
        sAgg[l] = ag / den;
    }
    __syncthreads();

    // ---- phase 4: out[i,:] = x[i,:] + agg @ out_w ----
    {
        float acc = 0.f;
        #pragma unroll 8
        for (int d = 0; d < 64; ++d)
            acc += sAgg[d] * out_w[d * DIMV + tid];
        const int o = (b * NN + i) * DIMV + tid;
        out[o] = x[o] + acc;
    }
}

// ---------------------------------------------------------------------------
extern "C" void kernel_launch(void* const* d_in, const int* in_sizes, int n_in,
                              void* d_out, int out_size, void* d_ws, size_t ws_size,
                              hipStream_t stream)
{
    const float* x       = (const float*)d_in[0];
    const float* y       = (const float*)d_in[1];
    const float* x_pos   = (const float*)d_in[2];
    const float* y_pos   = (const float*)d_in[3];
    const int*   mask    = (const int*)d_in[4];
    const float* g_w     = (const float*)d_in[5];
    const float* theta_w = (const float*)d_in[6];
    const float* phi_w   = (const float*)d_in[7];
    const float* pos_w1  = (const float*)d_in[8];
    const float* pos_b1  = (const float*)d_in[9];
    const float* pos_w2  = (const float*)d_in[10];
    const float* pos_b2  = (const float*)d_in[11];
    const float* attn_w1 = (const float*)d_in[12];
    const float* attn_b1 = (const float*)d_in[13];
    const float* attn_w2 = (const float*)d_in[14];
    const float* attn_b2 = (const float*)d_in[15];
    const float* out_w   = (const float*)d_in[16];

    float* q = (float*)d_ws;
    float* k = q + NB * NN * DI;
    float* v = k + NB * NN * DI;
    u16* w1t  = (u16*)(v + NB * NN * DI);   // 256*64
    u16* w2t  = w1t + 256 * 64;             // 64*256
    u16* pw2t = w2t + 64 * 256;             // 64*64

    prep_w<<<64, 256, 0, stream>>>(attn_w1, attn_w2, pos_w2, w1t, w2t, pw2t);
    prep_qkv<<<512, 256, 0, stream>>>(x, y, theta_w, phi_w, g_w, q, k, v);
    fused_attn<<<NB * NN, 256, 0, stream>>>(x, x_pos, y_pos, mask,
                                            pos_w1, pos_b1, pos_b2,
                                            attn_b1, attn_b2, out_w,
                                            q, k, v, w1t, w2t, pw2t,
                                            (float*)d_out);
}